// Round 4
// baseline (726.706 us; speedup 1.0000x reference)
//
#include <hip/hip_runtime.h>
#include <hip/hip_bf16.h>
#include <math.h>

#define BB 2
#define SS 1024
#define DIM 2048
#define HH 16
#define QR 1536
#define KVR 512
#define DN 128
#define DR 64
#define DV 128
#define QKD 192
#define NT (BB*SS)

typedef __attribute__((ext_vector_type(8))) short bhalf8;
typedef __attribute__((ext_vector_type(4))) float f32x4;

__device__ __forceinline__ unsigned short f2b(float f) {
  union { float f; unsigned u; } v; v.f = f;
  unsigned r = v.u + 0x7fffu + ((v.u >> 16) & 1u);
  return (unsigned short)(r >> 16);
}
__device__ __forceinline__ float b2f(unsigned short h) {
  union { unsigned u; float f; } v; v.u = ((unsigned)h) << 16;
  return v.f;
}

__device__ __forceinline__ void gload16(const void* g, void* l) {
  __builtin_amdgcn_global_load_lds((const __attribute__((address_space(1))) void*)g,
                                   (__attribute__((address_space(3))) void*)l, 16, 0, 0);
}

// ---------------- f32 -> bf16 convert ----------------
__global__ void cvt_k(const float* __restrict__ in, unsigned short* __restrict__ out, long n4) {
  long i = (long)blockIdx.x * 256 + threadIdx.x;
  if (i >= n4) return;
  float4 v = ((const float4*)in)[i];
  ushort4 o; o.x = f2b(v.x); o.y = f2b(v.y); o.z = f2b(v.z); o.w = f2b(v.w);
  ((ushort4*)out)[i] = o;
}

// wkT[h][c][d] = bf16(wk[h][d][c]), d<128, c<512
__global__ void wkT_k(const float* __restrict__ wk, unsigned short* __restrict__ wkT) {
  int idx = blockIdx.x * 256 + threadIdx.x;
  int d = idx & 127, c = (idx >> 7) & 511, h = idx >> 16;
  wkT[idx] = f2b(wk[((long)h * 256 + d) * 512 + c]);
}

// kcatT_swz[b][c][t ^ ((c&7)<<3)] = kcatb_swz[b][t][c ^ ((t&7)<<3)]
__global__ void kcT_k(const unsigned short* __restrict__ kc, unsigned short* __restrict__ kt) {
  int idx = blockIdx.x * 256 + threadIdx.x;
  int t = idx & 1023, c = (idx >> 10) & 511, b = idx >> 19;
  int csrc = c ^ ((t & 7) << 3);
  int tdst = t ^ ((c & 7) << 3);
  kt[((long)b * 512 + c) * 1024 + tdst] = kc[((long)b * SS + t) * 576 + csrc];
}

// ---------------- MFMA GEMM (unchanged, known-good) ----------------
template<int OBF, int CAUSAL, int XMODE, int KC>
__global__ __launch_bounds__(256) void gemm_mfma(
    const unsigned short* __restrict__ A, int lda, long sA,
    const unsigned short* __restrict__ B, int ldb, long sB, int bmod,
    void* __restrict__ C, int ldc, long sC,
    int M, int N, int K, const float* __restrict__ bias, float scale)
{
  int bx, by, bz;
  if (XMODE == 0) { bx = blockIdx.x; by = blockIdx.y; bz = blockIdx.z; }
  else {
    int L = blockIdx.x, xcd = L & 7, slot = L >> 3;
    if (XMODE == 1) {
      bx = ((xcd & 1) << 2) | (slot & 3);
      by = (((xcd >> 1) & 1) << 2) | ((slot >> 2) & 3);
      bz = (((xcd >> 2) & 1) << 2) | ((slot >> 4) & 3);
    } else {
      bx = ((xcd & 1) << 1) | (slot & 1);
      by = (((xcd >> 1) & 1) << 2) | ((slot >> 1) & 3);
      bz = (((xcd >> 2) & 1) << 2) | ((slot >> 3) & 3);
    }
  }
  const int m0 = by * 128, n0 = bx * 128;
  if (CAUSAL && n0 > m0 + 127) return;

  A += (long)bz * sA;
  B += (long)(bmod ? (bz % bmod) : bz) * sB;

  __shared__ unsigned short As[4096];
  __shared__ unsigned short Bs[4096];
  const int tid = threadIdx.x, l = tid & 63, w = tid >> 6;
  const int wr = w >> 1, wc = w & 1;
  const int rA = l >> 2;
  const int c8 = (((l & 3) ^ ((l >> 2) & 3)) << 3);

  f32x4 acc[4][4] = {};

  const unsigned short* Ab0 = A + (long)(m0 + w * 16 + rA) * lda + c8;
  const unsigned short* Ab1 = Ab0 + (long)64 * lda;
  int nb0 = n0 + w * 16 + rA;      if (nb0 > N - 1) nb0 = N - 1;
  int nb1 = n0 + 64 + w * 16 + rA; if (nb1 > N - 1) nb1 = N - 1;
  const unsigned short* Bb0 = B + (long)nb0 * ldb + c8;
  const unsigned short* Bb1 = B + (long)nb1 * ldb + c8;

  const int ko = (((l >> 4) ^ (l & 3)) << 3);
  const int Kend = KC ? ((m0 + 128 < K) ? m0 + 128 : K) : K;

  for (int k0 = 0; k0 < Kend; k0 += 32) {
    gload16(Ab0 + k0, &As[w * 512]);
    gload16(Ab1 + k0, &As[(w + 4) * 512]);
    gload16(Bb0 + k0, &Bs[w * 512]);
    gload16(Bb1 + k0, &Bs[(w + 4) * 512]);
    __syncthreads();
    bhalf8 af[4], bv[4];
#pragma unroll
    for (int m = 0; m < 4; ++m) {
      af[m] = *(const bhalf8*)&As[(wr * 64 + m * 16 + (l & 15)) * 32 + ko];
      bv[m] = *(const bhalf8*)&Bs[(wc * 64 + m * 16 + (l & 15)) * 32 + ko];
    }
#pragma unroll
    for (int m = 0; m < 4; ++m)
#pragma unroll
      for (int n = 0; n < 4; ++n)
        acc[m][n] = __builtin_amdgcn_mfma_f32_16x16x32_bf16(af[m], bv[n], acc[m][n], 0, 0, 0);
    __syncthreads();
  }

  const int ro = (l >> 4) << 2;
  const int co = l & 15;
#pragma unroll
  for (int m = 0; m < 4; ++m) {
    int row = m0 + wr * 64 + m * 16 + ro;
#pragma unroll
    for (int n = 0; n < 4; ++n) {
      int col = n0 + wc * 64 + n * 16 + co;
      if (col < N) {
        float bvl = bias ? bias[col] : 0.f;
#pragma unroll
        for (int r = 0; r < 4; ++r) {
          float v = acc[m][n][r] * scale + bvl;
          if (CAUSAL && (row + r) < col) v += -1e9f;
          long off = (long)bz * sC + (long)(row + r) * ldc + col;
          if (OBF) ((unsigned short*)C)[off] = f2b(v);
          else     ((float*)C)[off] = v;
        }
      }
    }
  }
}

// ---------------- RMSNorm fp32 -> bf16 (optional swizzled output) ----------------
template<int SWZ>
__global__ void rmsnorm_k(const float* __restrict__ in, int ldin,
                          unsigned short* __restrict__ out, int ldout,
                          const float* __restrict__ w, int N) {
  long row = blockIdx.x;
  const float* x = in + row * ldin;
  unsigned short* y = out + row * ldout;
  float ss = 0.f;
  for (int i = threadIdx.x; i < N; i += 256) { float u = x[i]; ss += u * u; }
  for (int o = 32; o > 0; o >>= 1) ss += __shfl_down(ss, o);
  __shared__ float red[4];
  int lane = threadIdx.x & 63, wid = threadIdx.x >> 6;
  if (lane == 0) red[wid] = ss;
  __syncthreads();
  float r = rsqrtf((red[0] + red[1] + red[2] + red[3]) / (float)N + 1e-6f);
  int sw = SWZ ? (((int)row & 7) << 3) : 0;
  for (int i = threadIdx.x; i < N; i += 256) y[i ^ sw] = f2b(x[i] * r * w[i]);
}

// ---------------- RoPE on q_pe, in-place bf16 ----------------
__global__ void rope_q_k(unsigned short* __restrict__ qb,
                         const float* __restrict__ cosT, const float* __restrict__ sinT) {
  int idx = blockIdx.x * 256 + threadIdx.x;
  int d = idx & 31, h = (idx >> 5) & 15, t = idx >> 9, s = t & (SS - 1);
  unsigned short* p = qb + (long)t * 3072 + h * QKD + DN;
  float x1 = b2f(p[d]), x2 = b2f(p[d + 32]);
  float c1 = cosT[s * DR + d],      s1 = sinT[s * DR + d];
  float c2 = cosT[s * DR + 32 + d], s2 = sinT[s * DR + 32 + d];
  p[d]      = f2b(x1 * c1 - x2 * s1);
  p[d + 32] = f2b(x2 * c2 + x1 * s2);
}

// ---------------- RoPE on k_pe -> kcatb (swizzled cols 512..575) ----------------
__global__ void rope_k_k(const float* __restrict__ kv, unsigned short* __restrict__ kc,
                         const float* __restrict__ cosT, const float* __restrict__ sinT) {
  int idx = blockIdx.x * 256 + threadIdx.x;
  int d = idx & 31, t = idx >> 5, s = t & (SS - 1);
  const float* p = kv + (long)t * 576 + 512;
  float x1 = p[d], x2 = p[d + 32];
  float c1 = cosT[s * DR + d],      s1 = sinT[s * DR + d];
  float c2 = cosT[s * DR + 32 + d], s2 = sinT[s * DR + 32 + d];
  unsigned short* o = kc + (long)t * 576;
  int sw = (t & 7) << 3;
  o[(512 + d) ^ sw]      = f2b(x1 * c1 - x2 * s1);
  o[(512 + d + 32) ^ sw] = f2b(x2 * c2 + x1 * s2);
}

// ---------------- copy q_pe (8 heads h0..h0+7) into qcat cols 512..575 ----------------
__global__ void copy_pe_k(const unsigned short* __restrict__ qb,
                          unsigned short* __restrict__ qcat, int h0) {
  int idx = blockIdx.x * 256 + threadIdx.x;   // 8*NT*64
  int d = idx & 63, t = (idx >> 6) & (NT - 1), z = idx >> 17;
  qcat[((long)z * NT + t) * 576 + 512 + d] = qb[(long)t * 3072 + (h0 + z) * QKD + DN + d];
}

// ---------------- fused flash attention over the 576-d latent ----------------
// grid: 256 blocks = qt(0..15) * 16 + b*8 + h(0..7).  4 waves, QTILE=64, KVTILE=64.
__global__ __launch_bounds__(256, 1) void flash_k(
    const unsigned short* __restrict__ qcat,   // [8][NT][576] linear
    const unsigned short* __restrict__ kcb,    // [NT][576] col-swizzled by (t&7)
    const unsigned short* __restrict__ kct,    // [B][512][1024] t-swizzled by (vc&7)
    unsigned short* __restrict__ omid)         // [8][NT][512]
{
  __shared__ __align__(16) char lds[147456];
  char* Kl = lds;                 // [64][1152B]
  char* Vl = lds + 73728;         // [512][128B]
  char* Pl = lds + 139264;        // 4 x [16][128B]

  const int idx = blockIdx.x;
  const int h = idx & 7, b = (idx >> 3) & 1, qt = idx >> 4;
  const int tid = threadIdx.x, l = tid & 63, w = tid >> 6;
  const int lo = l & 15, hi = l >> 4;

  // Q fragments in registers: rows qt*64 + w*16 + lo, K=576 (18 slices of 32)
  const unsigned short* qrow = qcat + ((long)h * NT + b * SS + qt * 64 + w * 16 + lo) * 576;
  bhalf8 qf[18];
#pragma unroll
  for (int ks = 0; ks < 18; ++ks)
    qf[ks] = *(const bhalf8*)(qrow + ks * 32 + hi * 8);

  f32x4 po[32] = {};                  // O[q=hi*4+r][vc=nv*16+lo]
  float mrow[4] = {-1e30f, -1e30f, -1e30f, -1e30f};
  float lrow[4] = {0.f, 0.f, 0.f, 0.f};

  const char* kcb_b = (const char*)kcb + (long)b * SS * 1152;
  const char* kct_b = (const char*)kct + (long)b * 512 * 2048;
  const float sc = 0.07216878364870323f;   // 1/sqrt(192)
  unsigned short* Pw = (unsigned short*)(Pl + w * 2048);

  for (int st = 0; st <= qt; ++st) {
    const int kv0 = st * 64;
    // stage K tile: 73728 B linear copy (storage is pre-swizzled)
    for (int i = w * 18; i < w * 18 + 18; ++i) {
      int flat = i * 1024 + l * 16;
      int t = flat / 1152;
      int cb = flat - t * 1152;
      gload16(kcb_b + (long)(kv0 + t) * 1152 + cb, Kl + flat);
    }
    // stage VT tile: 65536 B
    for (int i = w * 16; i < w * 16 + 16; ++i) {
      int flat = i * 1024 + l * 16;
      int vc = flat >> 7;
      int cb = flat & 127;
      gload16(kct_b + (long)vc * 2048 + kv0 * 2 + cb, Vl + flat);
    }
    __syncthreads();

    // QK^T -> S[q=hi*4+r][kv=n*16+lo]
    f32x4 sa[4] = {};
#pragma unroll
    for (int n = 0; n < 4; ++n) {
      const int kv = n * 16 + lo;
      const char* krow = Kl + kv * 1152;
#pragma unroll
      for (int ks = 0; ks < 18; ++ks) {
        int byt = ((ks * 32 + hi * 8) * 2) ^ ((kv & 7) << 4);
        bhalf8 bf = *(const bhalf8*)(krow + byt);
        sa[n] = __builtin_amdgcn_mfma_f32_16x16x32_bf16(qf[ks], bf, sa[n], 0, 0, 0);
      }
    }
    // scale + causal mask (diagonal step only)
    if (st == qt) {
#pragma unroll
      for (int n = 0; n < 4; ++n) {
        const int kv = n * 16 + lo;
#pragma unroll
        for (int r = 0; r < 4; ++r) {
          int q = w * 16 + hi * 4 + r;
          sa[n][r] = (kv > q) ? -1e30f : sa[n][r] * sc;
        }
      }
    } else {
#pragma unroll
      for (int n = 0; n < 4; ++n)
#pragma unroll
        for (int r = 0; r < 4; ++r) sa[n][r] *= sc;
    }
    // online softmax: row stats over 16 lanes sharing hi
    float fac[4];
#pragma unroll
    for (int r = 0; r < 4; ++r) {
      float v = fmaxf(fmaxf(sa[0][r], sa[1][r]), fmaxf(sa[2][r], sa[3][r]));
      v = fmaxf(v, __shfl_xor(v, 1));
      v = fmaxf(v, __shfl_xor(v, 2));
      v = fmaxf(v, __shfl_xor(v, 4));
      v = fmaxf(v, __shfl_xor(v, 8));
      float mn = fmaxf(mrow[r], v);
      fac[r] = __expf(mrow[r] - mn);
      mrow[r] = mn;
    }
    float rs[4] = {0.f, 0.f, 0.f, 0.f};
#pragma unroll
    for (int n = 0; n < 4; ++n)
#pragma unroll
      for (int r = 0; r < 4; ++r) {
        float p = __expf(sa[n][r] - mrow[r]);
        sa[n][r] = p;
        rs[r] += p;
      }
#pragma unroll
    for (int r = 0; r < 4; ++r) {
      float v = rs[r];
      v += __shfl_xor(v, 1); v += __shfl_xor(v, 2);
      v += __shfl_xor(v, 4); v += __shfl_xor(v, 8);
      lrow[r] = lrow[r] * fac[r] + v;
    }
    // rescale O acc
#pragma unroll
    for (int nv = 0; nv < 32; ++nv)
#pragma unroll
      for (int r = 0; r < 4; ++r) po[nv][r] *= fac[r];
    // P -> bf16 -> wave-private LDS (swizzled rows of 128B)
#pragma unroll
    for (int n = 0; n < 4; ++n)
#pragma unroll
      for (int r = 0; r < 4; ++r) {
        int q = hi * 4 + r, kv = n * 16 + lo;
        int byt = (kv * 2) ^ ((q & 7) << 4);
        *(unsigned short*)((char*)Pw + q * 128 + byt) = f2b(sa[n][r]);
      }
    // PV: O += P @ V^T-tiles
#pragma unroll
    for (int ts = 0; ts < 2; ++ts) {
      int pbyt = ((ts * 32 + hi * 8) * 2) ^ ((lo & 7) << 4);
      bhalf8 pa = *(const bhalf8*)((char*)Pw + lo * 128 + pbyt);
#pragma unroll
      for (int nv = 0; nv < 32; ++nv) {
        int vc = nv * 16 + lo;
        int vbyt = ((ts * 32 + hi * 8) * 2) ^ ((vc & 7) << 4);
        bhalf8 vb = *(const bhalf8*)(Vl + vc * 128 + vbyt);
        po[nv] = __builtin_amdgcn_mfma_f32_16x16x32_bf16(pa, vb, po[nv], 0, 0, 0);
      }
    }
    __syncthreads();
  }

  // epilogue: O / l -> omid
  unsigned short* orow = omid + ((long)h * NT + b * SS + qt * 64) * 512;
  float inv[4];
#pragma unroll
  for (int r = 0; r < 4; ++r) inv[r] = 1.f / lrow[r];
#pragma unroll
  for (int nv = 0; nv < 32; ++nv)
#pragma unroll
    for (int r = 0; r < 4; ++r) {
      int q = w * 16 + hi * 4 + r;
      orow[(long)q * 512 + nv * 16 + lo] = f2b(po[nv][r] * inv[r]);
    }
}

// ---------------- launch ----------------
extern "C" void kernel_launch(void* const* d_in, const int* in_sizes, int n_in,
                              void* d_out, int out_size, void* d_ws, size_t ws_size,
                              hipStream_t stream) {
  const float* x        = (const float*)d_in[0];
  const float* wq_a_w   = (const float*)d_in[2];
  const float* wq_a_b   = (const float*)d_in[3];
  const float* q_norm_w = (const float*)d_in[4];
  const float* wq_b_w   = (const float*)d_in[5];
  const float* wq_b_b   = (const float*)d_in[6];
  const float* wkv_a_w  = (const float*)d_in[7];
  const float* wkv_a_b  = (const float*)d_in[8];
  const float* kv_norm_w= (const float*)d_in[9];
  const float* wk_b_w   = (const float*)d_in[10];
  const float* wo_w     = (const float*)d_in[11];
  const float* wo_bias  = (const float*)d_in[12];
  const float* cosT     = (const float*)d_in[13];
  const float* sinT     = (const float*)d_in[14];
  float* out = (float*)d_out;

  char* W = (char*)d_ws;
  unsigned short* wkb_b  = (unsigned short*)(W + 0);          // 4 MB
  unsigned short* wkT_b  = (unsigned short*)(W + 4194304);    // 2 MB
  unsigned short* qb     = (unsigned short*)(W + 6291456);    // 12 MB [NT][3072]
  unsigned short* wqa_b  = (unsigned short*)(W + 6291456);    // alias (dead before qb)
  unsigned short* ohead  = (unsigned short*)(W + 18874368);   // 8 MB  [NT][2048]
  unsigned short* xb     = (unsigned short*)(W + 18874368);   // alias (dead before ohead)
  unsigned short* kcatb  = (unsigned short*)(W + 27262976);   // 2.25 MB [NT][576] swz
  unsigned short* kcatT  = (unsigned short*)(W + 29622272);   // 2 MB  [B][512][1024] swz
  // loop region @31,719,424 (35.65 MB)
  unsigned short* qcat   = (unsigned short*)(W + 31719424);   // 18.87 MB [8][NT][576]
  unsigned short* o_mid  = (unsigned short*)(W + 50593792);   // 16.78 MB [8][NT][512]
  unsigned short* wo_b16 = (unsigned short*)(W + 31719424);   // 8 MB (after loop, qcat dead)
  // pre-loop aliases within loop region
  float*          qn_f32 = (float*)        (W + 31719424);    // 12 MB
  float*          kv_f32 = (float*)        (W + 31719424);    // 4.5 MB (after qn dead)
  unsigned short* qnb    = (unsigned short*)(W + 44302336);   // 6 MB
  unsigned short* wqb_b  = (unsigned short*)(W + 50593792);   // 9 MB
  unsigned short* wkva_b = (unsigned short*)(W + 60030976);   // 2.25 MB (end 62,390,272)

  // conversions
  cvt_k<<<4096, 256, 0, stream>>>(x, xb, (long)NT * DIM / 4);
  cvt_k<<<3072, 256, 0, stream>>>(wq_a_w, wqa_b, (long)QR * DIM / 4);
  cvt_k<<<4608, 256, 0, stream>>>(wq_b_w, wqb_b, (long)3072 * QR / 4);
  cvt_k<<<1152, 256, 0, stream>>>(wkv_a_w, wkva_b, (long)576 * DIM / 4);
  cvt_k<<<2048, 256, 0, stream>>>(wk_b_w, wkb_b, (long)HH * 256 * KVR / 4);
  wkT_k<<<4096, 256, 0, stream>>>(wk_b_w, wkT_b);

  // q_a: qn = x @ wq_a^T (fp32)
  gemm_mfma<0,0,0,0><<<dim3(QR/128, NT/128, 1), 256, 0, stream>>>(
      xb, DIM, 0, wqa_b, DIM, 0, 0, qn_f32, QR, 0, NT, QR, DIM, wq_a_b, 1.f);
  rmsnorm_k<0><<<NT, 256, 0, stream>>>(qn_f32, QR, qnb, QR, q_norm_w, QR);
  // q_b: qb = qnb @ wq_b^T (bf16)
  gemm_mfma<1,0,0,0><<<dim3(3072/128, NT/128, 1), 256, 0, stream>>>(
      qnb, QR, 0, wqb_b, QR, 0, 0, qb, 3072, 0, NT, 3072, QR, wq_b_b, 1.f);
  rope_q_k<<<4096, 256, 0, stream>>>(qb, cosT, sinT);
  // kv_a: kv = x @ wkv_a^T (fp32) -- note: qn_f32 must be dead (it is: qnb holds norm)
  gemm_mfma<0,0,0,0><<<dim3(5, NT/128, 1), 256, 0, stream>>>(
      xb, DIM, 0, wkva_b, DIM, 0, 0, kv_f32, 576, 0, NT, 576, DIM, wkv_a_b, 1.f);
  rmsnorm_k<1><<<NT, 256, 0, stream>>>(kv_f32, 576, kcatb, 576, kv_norm_w, KVR);
  rope_k_k<<<256, 256, 0, stream>>>(kv_f32, kcatb, cosT, sinT);
  kcT_k<<<4096, 256, 0, stream>>>(kcatb, kcatT);

  for (int p = 0; p < 2; ++p) {
    int h0 = p * 8;
    // q_abs: qcat[z][:, :512] = q_nope_{h0+z} @ wkT[h0+z]^T
    gemm_mfma<1,0,0,0><<<dim3(4, NT/128, 8), 256, 0, stream>>>(
        qb + h0 * QKD, 3072, QKD,
        wkT_b + (long)h0 * KVR * DN, DN, (long)KVR * DN, 0,
        qcat, 576, (long)NT * 576, NT, KVR, DN, nullptr, 1.f);
    copy_pe_k<<<4096, 256, 0, stream>>>(qb, qcat, h0);
    // fused attention for 8 heads
    flash_k<<<256, 256, 0, stream>>>(qcat, kcatb, kcatT, o_mid);
    // o_head[:, (h0+z)*128..] = o_mid[z] @ wkv_b_v^T
    gemm_mfma<1,0,0,0><<<dim3(1, NT/128, 8), 256, 0, stream>>>(
        o_mid, KVR, (long)NT * KVR,
        wkb_b + ((long)h0 * 256 + DN) * KVR, KVR, (long)256 * KVR, 0,
        ohead + h0 * DV, HH * DV, DV, NT, DV, KVR, nullptr, 1.f);
  }

  // wo conversion (qcat region dead), final projection (fp32 out)
  cvt_k<<<4096, 256, 0, stream>>>(wo_w, wo_b16, (long)DIM * DIM / 4);
  gemm_mfma<0,0,0,0><<<dim3(DIM/128, NT/128, 1), 256, 0, stream>>>(
      ohead, 2048, 0, wo_b16, 2048, 0, 0, out, DIM, 0, NT, DIM, 2048, wo_bias, 1.f);
}